// Round 2
// baseline (82.616 us; speedup 1.0000x reference)
//
#include <hip/hip_runtime.h>

// Problem constants (match reference setup_inputs)
#define BB 4096   // B
#define NN 8192   // N = 2B
#define DD 256    // D

// One wave (64 lanes) per row: float4 load -> 4 elems/lane, butterfly
// max+first-index reduce, lane0 writes row stats + histogram atomic.
__global__ void rowmax_kernel(const float* __restrict__ out_a,
                              const float* __restrict__ out_b,
                              float* __restrict__ max_feat,
                              int* __restrict__ idx_max,
                              float* __restrict__ num_max /* = d_out+1, 256 bins */) {
    int gtid = blockIdx.x * blockDim.x + threadIdx.x;
    int row  = gtid >> 6;          // wave id
    int lane = threadIdx.x & 63;
    if (row >= NN) return;

    const float* rowp = (row < BB) ? (out_a + (size_t)row * DD)
                                   : (out_b + (size_t)(row - BB) * DD);
    float4 v = *reinterpret_cast<const float4*>(rowp + lane * 4);

    float best = v.x; int bi = lane * 4;
    if (v.y > best) { best = v.y; bi = lane * 4 + 1; }
    if (v.z > best) { best = v.z; bi = lane * 4 + 2; }
    if (v.w > best) { best = v.w; bi = lane * 4 + 3; }

    // 64-lane butterfly reduce; tie -> lower index (jnp.argmax = first max)
    #pragma unroll
    for (int off = 32; off >= 1; off >>= 1) {
        float ov = __shfl_xor(best, off, 64);
        int   oi = __shfl_xor(bi,   off, 64);
        if (ov > best || (ov == best && oi < bi)) { best = ov; bi = oi; }
    }

    if (lane == 0) {
        max_feat[row] = best;
        idx_max[row]  = bi;
        atomicAdd(&num_max[bi], 1.0f);
    }
}

// One thread per row: 2 gathered loads, loss term, wave-reduce, 1 atomic/wave.
__global__ void loss_kernel(const float* __restrict__ out_a,
                            const float* __restrict__ out_b,
                            const int* __restrict__ neg_choice,
                            const float* __restrict__ max_feat,
                            const int* __restrict__ idx_max,
                            float* __restrict__ loss /* = d_out[0] */) {
    int r = blockIdx.x * blockDim.x + threadIdx.x;
    float term = 0.0f;
    if (r < NN) {
        int pair = (r < BB) ? (r + BB) : (r - BB);
        int e1   = (r < BB) ? r : (r - BB);   // min(r, pair)
        int e2   = e1 + BB;                   // max(r, pair)
        int c = neg_choice[r];
        c += (c >= e1);
        c += (c >= e2);

        const float* rowp = (r < BB) ? (out_a + (size_t)r * DD)
                                     : (out_b + (size_t)(r - BB) * DD);
        float mf  = max_feat[r];
        float pos = mf - rowp[idx_max[pair]];
        float neg = mf - rowp[idx_max[c]];
        float md  = fmaxf(1.0f - neg, 0.0f);
        term = pos + md * md;
    }
    #pragma unroll
    for (int off = 32; off >= 1; off >>= 1)
        term += __shfl_xor(term, off, 64);
    if ((threadIdx.x & 63) == 0)
        atomicAdd(loss, 0.5f * term);
}

extern "C" void kernel_launch(void* const* d_in, const int* in_sizes, int n_in,
                              void* d_out, int out_size, void* d_ws, size_t ws_size,
                              hipStream_t stream) {
    const float* out_a      = (const float*)d_in[0];
    const float* out_b      = (const float*)d_in[1];
    const int*   neg_choice = (const int*)d_in[2];
    float* out = (float*)d_out;           // out[0]=loss, out[1..256]=num_max

    float* max_feat = (float*)d_ws;
    int*   idx_max  = (int*)((char*)d_ws + NN * sizeof(float));

    // d_out is poisoned before every replay; zero it (we accumulate atomically).
    hipMemsetAsync(d_out, 0, (size_t)out_size * sizeof(float), stream);

    // 8192 waves, 4 waves per 256-thread block -> 2048 blocks
    rowmax_kernel<<<NN / 4, 256, 0, stream>>>(out_a, out_b, max_feat, idx_max, out + 1);

    loss_kernel<<<NN / 256, 256, 0, stream>>>(out_a, out_b, neg_choice,
                                              max_feat, idx_max, out);
}